// Round 15
// baseline (343.155 us; speedup 1.0000x reference)
//
#include <hip/hip_runtime.h>
#include <hip/hip_bf16.h>
#include <math.h>

#define N_NODES 20000
#define N_EDGES 640000
#define P_PATH 512
#define S_PATH 64
#define BIN_CAP 96  // max in-degree guard; Binomial(640K,1/20K) max ~57 over 20K nodes

static __device__ __forceinline__ unsigned short f2bf(float f) {
    unsigned int b = __float_as_uint(f);
    unsigned int r = (b + 0x7fffu + ((b >> 16) & 1u)) >> 16;
    return (unsigned short)r;
}

// unpack uint2 (4 packed bf16: low half = even elem) and accumulate into float4
static __device__ __forceinline__ void bf16_acc(float4& acc, uint2 u) {
    acc.x += __uint_as_float(u.x << 16);
    acc.y += __uint_as_float(u.x & 0xffff0000u);
    acc.z += __uint_as_float(u.y << 16);
    acc.w += __uint_as_float(u.y & 0xffff0000u);
}

static __device__ __forceinline__ float4 bf16_unpack(uint2 u) {
    float4 v;
    v.x = __uint_as_float(u.x << 16);
    v.y = __uint_as_float(u.x & 0xffff0000u);
    v.z = __uint_as_float(u.y << 16);
    v.w = __uint_as_float(u.y & 0xffff0000u);
    return v;
}

static __device__ __forceinline__ uint2 bf16_pack(float4 v) {
    uint2 u;
    u.x = (unsigned int)f2bf(v.x) | ((unsigned int)f2bf(v.y) << 16);
    u.y = (unsigned int)f2bf(v.z) | ((unsigned int)f2bf(v.w) << 16);
    return u;
}

// ---------------- binned adjacency build ----------------
__global__ __launch_bounds__(256) void zero_ints(int* p, int n) {
    int i = blockIdx.x * 256 + threadIdx.x;
    if (i < n) p[i] = 0;
}

// single pass: histogram + scatter; bins stored as ushort (node ids < 65536)
__global__ __launch_bounds__(256) void fill_bins(const int* __restrict__ src,
                                                 const int* __restrict__ dst,
                                                 int* __restrict__ counts,
                                                 unsigned short* __restrict__ bins, int n) {
    int e = blockIdx.x * 256 + threadIdx.x;
    if (e < n) {
        int node = dst[e];
        int pos = atomicAdd(&counts[node], 1);
        if (pos < BIN_CAP) bins[node * BIN_CAP + pos] = (unsigned short)src[e];
    }
}

// ---------------- GIN aggregation ----------------
// fp32 variant (layer 1 reads input h0)
__global__ __launch_bounds__(256) void gin_agg4(const float* __restrict__ h_in,
                                                const int* __restrict__ counts,
                                                const unsigned short* __restrict__ bins,
                                                float* __restrict__ agg, int dim4, int n_nodes) {
    int id = blockIdx.x * 256 + threadIdx.x;
    if (id >= n_nodes * dim4) return;
    int node = id / dim4;
    int d4 = id - node * dim4;
    int cnt = counts[node];
    if (cnt > BIN_CAP) cnt = BIN_CAP;
    const unsigned short* bp = bins + node * BIN_CAP;
    const float4* hp = reinterpret_cast<const float4*>(h_in);
    float4 a0 = {0,0,0,0}, a1 = {0,0,0,0}, a2 = {0,0,0,0}, a3 = {0,0,0,0};
    float4 a4 = {0,0,0,0}, a5 = {0,0,0,0}, a6 = {0,0,0,0}, a7 = {0,0,0,0};
    int e = 0;
    for (; e + 8 <= cnt; e += 8) {
        int s0 = bp[e + 0], s1 = bp[e + 1], s2 = bp[e + 2], s3 = bp[e + 3];
        int s4 = bp[e + 4], s5 = bp[e + 5], s6 = bp[e + 6], s7 = bp[e + 7];
        float4 v0 = hp[(size_t)s0 * dim4 + d4];
        float4 v1 = hp[(size_t)s1 * dim4 + d4];
        float4 v2 = hp[(size_t)s2 * dim4 + d4];
        float4 v3 = hp[(size_t)s3 * dim4 + d4];
        float4 v4 = hp[(size_t)s4 * dim4 + d4];
        float4 v5 = hp[(size_t)s5 * dim4 + d4];
        float4 v6 = hp[(size_t)s6 * dim4 + d4];
        float4 v7 = hp[(size_t)s7 * dim4 + d4];
        a0.x += v0.x; a0.y += v0.y; a0.z += v0.z; a0.w += v0.w;
        a1.x += v1.x; a1.y += v1.y; a1.z += v1.z; a1.w += v1.w;
        a2.x += v2.x; a2.y += v2.y; a2.z += v2.z; a2.w += v2.w;
        a3.x += v3.x; a3.y += v3.y; a3.z += v3.z; a3.w += v3.w;
        a4.x += v4.x; a4.y += v4.y; a4.z += v4.z; a4.w += v4.w;
        a5.x += v5.x; a5.y += v5.y; a5.z += v5.z; a5.w += v5.w;
        a6.x += v6.x; a6.y += v6.y; a6.z += v6.z; a6.w += v6.w;
        a7.x += v7.x; a7.y += v7.y; a7.z += v7.z; a7.w += v7.w;
    }
    for (; e < cnt; ++e) {
        float4 v = hp[(size_t)bp[e] * dim4 + d4];
        a0.x += v.x; a0.y += v.y; a0.z += v.z; a0.w += v.w;
    }
    float4 r;
    r.x = (a0.x + a1.x) + (a2.x + a3.x) + (a4.x + a5.x) + (a6.x + a7.x);
    r.y = (a0.y + a1.y) + (a2.y + a3.y) + (a4.y + a5.y) + (a6.y + a7.y);
    r.z = (a0.z + a1.z) + (a2.z + a3.z) + (a4.z + a5.z) + (a6.z + a7.z);
    r.w = (a0.w + a1.w) + (a2.w + a3.w) + (a4.w + a5.w) + (a6.w + a7.w);
    reinterpret_cast<float4*>(agg)[id] = r;
}

// bf16-shadow variant (layers 2-4): halves gather bytes; fp32 accumulate.
__global__ __launch_bounds__(256) void gin_agg4_bf16(const unsigned short* __restrict__ hb,
                                                     const int* __restrict__ counts,
                                                     const unsigned short* __restrict__ bins,
                                                     float* __restrict__ agg, int dim4,
                                                     int n_nodes) {
    int id = blockIdx.x * 256 + threadIdx.x;
    if (id >= n_nodes * dim4) return;
    int node = id / dim4;
    int d4 = id - node * dim4;
    int cnt = counts[node];
    if (cnt > BIN_CAP) cnt = BIN_CAP;
    const unsigned short* bp = bins + node * BIN_CAP;
    const uint2* hp = reinterpret_cast<const uint2*>(hb);  // one uint2 = 4 bf16
    float4 a0 = {0,0,0,0}, a1 = {0,0,0,0}, a2 = {0,0,0,0}, a3 = {0,0,0,0};
    float4 a4 = {0,0,0,0}, a5 = {0,0,0,0}, a6 = {0,0,0,0}, a7 = {0,0,0,0};
    int e = 0;
    for (; e + 8 <= cnt; e += 8) {
        int s0 = bp[e + 0], s1 = bp[e + 1], s2 = bp[e + 2], s3 = bp[e + 3];
        int s4 = bp[e + 4], s5 = bp[e + 5], s6 = bp[e + 6], s7 = bp[e + 7];
        uint2 u0 = hp[(size_t)s0 * dim4 + d4];
        uint2 u1 = hp[(size_t)s1 * dim4 + d4];
        uint2 u2 = hp[(size_t)s2 * dim4 + d4];
        uint2 u3 = hp[(size_t)s3 * dim4 + d4];
        uint2 u4 = hp[(size_t)s4 * dim4 + d4];
        uint2 u5 = hp[(size_t)s5 * dim4 + d4];
        uint2 u6 = hp[(size_t)s6 * dim4 + d4];
        uint2 u7 = hp[(size_t)s7 * dim4 + d4];
        bf16_acc(a0, u0); bf16_acc(a1, u1); bf16_acc(a2, u2); bf16_acc(a3, u3);
        bf16_acc(a4, u4); bf16_acc(a5, u5); bf16_acc(a6, u6); bf16_acc(a7, u7);
    }
    for (; e < cnt; ++e) {
        uint2 u = hp[(size_t)bp[e] * dim4 + d4];
        bf16_acc(a0, u);
    }
    float4 r;
    r.x = (a0.x + a1.x) + (a2.x + a3.x) + (a4.x + a5.x) + (a6.x + a7.x);
    r.y = (a0.y + a1.y) + (a2.y + a3.y) + (a4.y + a5.y) + (a6.y + a7.y);
    r.z = (a0.z + a1.z) + (a2.z + a3.z) + (a4.z + a5.z) + (a6.z + a7.z);
    r.w = (a0.w + a1.w) + (a2.w + a3.w) + (a4.w + a5.w) + (a6.w + a7.w);
    reinterpret_cast<float4*>(agg)[id] = r;
}

// Register-tiled fp32 GEMM, 64n x 64j tile; also writes bf16 shadow of output.
template <int IN, int OUT>
__global__ __launch_bounds__(256) void gin_linear_t(const float* __restrict__ h_in,
                                                    const float* __restrict__ agg,
                                                    const float* __restrict__ W,
                                                    const float* __restrict__ b,
                                                    float* __restrict__ h_out,
                                                    unsigned short* __restrict__ sh_out,
                                                    int n_nodes) {
    constexpr int KC = (IN >= 64) ? 64 : IN;
    constexpr int KC4 = KC / 4;
    __shared__ float Xs[KC][64];
    __shared__ float Ws[KC][64];
    int tid = threadIdx.x;
    int node0 = blockIdx.x * 64;
    int j0 = blockIdx.y * 64;
    int tx = tid & 15, ty = tid >> 4;
    float acc[4][4] = {};
    for (int kc = 0; kc < IN; kc += KC) {
        for (int i = tid; i < KC4 * 64; i += 256) {
            int l = i & 63;
            int k4 = i >> 6;
            int node = node0 + l;
            float4 v = {0.f, 0.f, 0.f, 0.f};
            if (node < n_nodes) {
                const float4* hp =
                    reinterpret_cast<const float4*>(h_in + (size_t)node * IN + kc) + k4;
                const float4* ap =
                    reinterpret_cast<const float4*>(agg + (size_t)node * IN + kc) + k4;
                float4 a = *hp, g = *ap;
                v.x = a.x + g.x; v.y = a.y + g.y; v.z = a.z + g.z; v.w = a.w + g.w;
            }
            Xs[k4 * 4 + 0][l] = v.x;
            Xs[k4 * 4 + 1][l] = v.y;
            Xs[k4 * 4 + 2][l] = v.z;
            Xs[k4 * 4 + 3][l] = v.w;
            float4 wv = *(reinterpret_cast<const float4*>(W + (size_t)(j0 + l) * IN + kc) + k4);
            Ws[k4 * 4 + 0][l] = wv.x;
            Ws[k4 * 4 + 1][l] = wv.y;
            Ws[k4 * 4 + 2][l] = wv.z;
            Ws[k4 * 4 + 3][l] = wv.w;
        }
        __syncthreads();
#pragma unroll 8
        for (int k = 0; k < KC; ++k) {
            float4 a = *reinterpret_cast<const float4*>(&Xs[k][ty * 4]);
            float4 w = *reinterpret_cast<const float4*>(&Ws[k][tx * 4]);
            acc[0][0] += a.x * w.x; acc[0][1] += a.x * w.y; acc[0][2] += a.x * w.z; acc[0][3] += a.x * w.w;
            acc[1][0] += a.y * w.x; acc[1][1] += a.y * w.y; acc[1][2] += a.y * w.z; acc[1][3] += a.y * w.w;
            acc[2][0] += a.z * w.x; acc[2][1] += a.z * w.y; acc[2][2] += a.z * w.z; acc[2][3] += a.z * w.w;
            acc[3][0] += a.w * w.x; acc[3][1] += a.w * w.y; acc[3][2] += a.w * w.z; acc[3][3] += a.w * w.w;
        }
        __syncthreads();
    }
    float4 bj = *reinterpret_cast<const float4*>(b + j0 + tx * 4);
#pragma unroll
    for (int r = 0; r < 4; ++r) {
        int node = node0 + ty * 4 + r;
        if (node < n_nodes) {
            float4 o;
            o.x = fmaxf(acc[r][0] + bj.x, 0.f);
            o.y = fmaxf(acc[r][1] + bj.y, 0.f);
            o.z = fmaxf(acc[r][2] + bj.z, 0.f);
            o.w = fmaxf(acc[r][3] + bj.w, 0.f);
            *reinterpret_cast<float4*>(h_out + (size_t)node * OUT + j0 + tx * 4) = o;
            ushort4 us;
            us.x = f2bf(o.x); us.y = f2bf(o.y); us.z = f2bf(o.z); us.w = f2bf(o.w);
            *reinterpret_cast<ushort4*>(sh_out + (size_t)node * OUT + j0 + tx * 4) = us;
        }
    }
}

// 128-node x 64-j tile for L4 (IN=128): no shadow (attn reads fp32 h4).
template <int IN, int OUT>
__global__ __launch_bounds__(256) void gin_linear_128(const float* __restrict__ h_in,
                                                      const float* __restrict__ agg,
                                                      const float* __restrict__ W,
                                                      const float* __restrict__ b,
                                                      float* __restrict__ h_out, int n_nodes) {
    constexpr int KC = 32, KC4 = 8;
    constexpr int XSS = 132;
    constexpr int WSS = 68;
    __shared__ float Xs[KC * XSS];
    __shared__ float Ws[KC * WSS];
    int tid = threadIdx.x;
    int node0 = blockIdx.x * 128;
    int j0 = blockIdx.y * 64;
    int tx = tid & 15, ty = tid >> 4;
    float acc[8][4] = {};
    for (int kc = 0; kc < IN; kc += KC) {
        for (int i = tid; i < 128 * KC4; i += 256) {
            int node_l = i >> 3;
            int k4 = i & 7;
            int node = node0 + node_l;
            float4 v = {0.f, 0.f, 0.f, 0.f};
            if (node < n_nodes) {
                float4 a = *(reinterpret_cast<const float4*>(h_in + (size_t)node * IN + kc) + k4);
                float4 g = *(reinterpret_cast<const float4*>(agg + (size_t)node * IN + kc) + k4);
                v.x = a.x + g.x; v.y = a.y + g.y; v.z = a.z + g.z; v.w = a.w + g.w;
            }
            Xs[(k4 * 4 + 0) * XSS + node_l] = v.x;
            Xs[(k4 * 4 + 1) * XSS + node_l] = v.y;
            Xs[(k4 * 4 + 2) * XSS + node_l] = v.z;
            Xs[(k4 * 4 + 3) * XSS + node_l] = v.w;
        }
        for (int i = tid; i < 64 * KC4; i += 256) {
            int jl = i >> 3;
            int k4 = i & 7;
            float4 wv = *(reinterpret_cast<const float4*>(W + (size_t)(j0 + jl) * IN + kc) + k4);
            Ws[(k4 * 4 + 0) * WSS + jl] = wv.x;
            Ws[(k4 * 4 + 1) * WSS + jl] = wv.y;
            Ws[(k4 * 4 + 2) * WSS + jl] = wv.z;
            Ws[(k4 * 4 + 3) * WSS + jl] = wv.w;
        }
        __syncthreads();
#pragma unroll 8
        for (int k = 0; k < KC; ++k) {
            float4 a0 = *reinterpret_cast<const float4*>(&Xs[k * XSS + ty * 8]);
            float4 a1 = *reinterpret_cast<const float4*>(&Xs[k * XSS + ty * 8 + 4]);
            float4 w = *reinterpret_cast<const float4*>(&Ws[k * WSS + tx * 4]);
            acc[0][0] += a0.x * w.x; acc[0][1] += a0.x * w.y; acc[0][2] += a0.x * w.z; acc[0][3] += a0.x * w.w;
            acc[1][0] += a0.y * w.x; acc[1][1] += a0.y * w.y; acc[1][2] += a0.y * w.z; acc[1][3] += a0.y * w.w;
            acc[2][0] += a0.z * w.x; acc[2][1] += a0.z * w.y; acc[2][2] += a0.z * w.z; acc[2][3] += a0.z * w.w;
            acc[3][0] += a0.w * w.x; acc[3][1] += a0.w * w.y; acc[3][2] += a0.w * w.z; acc[3][3] += a0.w * w.w;
            acc[4][0] += a1.x * w.x; acc[4][1] += a1.x * w.y; acc[4][2] += a1.x * w.z; acc[4][3] += a1.x * w.w;
            acc[5][0] += a1.y * w.x; acc[5][1] += a1.y * w.y; acc[5][2] += a1.y * w.z; acc[5][3] += a1.y * w.w;
            acc[6][0] += a1.z * w.x; acc[6][1] += a1.z * w.y; acc[6][2] += a1.z * w.z; acc[6][3] += a1.z * w.w;
            acc[7][0] += a1.w * w.x; acc[7][1] += a1.w * w.y; acc[7][2] += a1.w * w.z; acc[7][3] += a1.w * w.w;
        }
        __syncthreads();
    }
    float4 bj = *reinterpret_cast<const float4*>(b + j0 + tx * 4);
#pragma unroll
    for (int r = 0; r < 8; ++r) {
        int node = node0 + ty * 8 + r;
        if (node < n_nodes) {
            float4 o;
            o.x = fmaxf(acc[r][0] + bj.x, 0.f);
            o.y = fmaxf(acc[r][1] + bj.y, 0.f);
            o.z = fmaxf(acc[r][2] + bj.z, 0.f);
            o.w = fmaxf(acc[r][3] + bj.w, 0.f);
            *reinterpret_cast<float4*>(h_out + (size_t)node * OUT + j0 + tx * 4) = o;
        }
    }
}

// layer-1 (IN=8) small kernel; writes fp32 + bf16 shadow
template <int IN, int OUT, int NG, int NB>
__global__ __launch_bounds__(OUT * NG) void gin_linear_s(const float* __restrict__ h_in,
                                                         const float* __restrict__ agg,
                                                         const float* __restrict__ W,
                                                         const float* __restrict__ b,
                                                         float* __restrict__ h_out,
                                                         unsigned short* __restrict__ sh_out,
                                                         int n_nodes) {
    constexpr int NODES = NG * NB;
    constexpr int K4 = IN / 4;
    __shared__ float4 X[NODES * K4];
    int tid = threadIdx.x;
    int node0 = blockIdx.x * NODES;
    const float4* hp = reinterpret_cast<const float4*>(h_in);
    const float4* ap = reinterpret_cast<const float4*>(agg);
    for (int i = tid; i < NODES * K4; i += OUT * NG) {
        int node = node0 + i / K4;
        float4 v = {0.f, 0.f, 0.f, 0.f};
        if (node < n_nodes) {
            size_t idx = (size_t)node0 * K4 + i;
            float4 a = hp[idx], g = ap[idx];
            v.x = a.x + g.x; v.y = a.y + g.y; v.z = a.z + g.z; v.w = a.w + g.w;
        }
        X[i] = v;
    }
    __syncthreads();
    int grp = tid / OUT, j = tid - grp * OUT;
    float4 wr[K4];
    const float4* Wp = reinterpret_cast<const float4*>(W + (size_t)j * IN);
#pragma unroll
    for (int k = 0; k < K4; ++k) wr[k] = Wp[k];
    float bj = b[j];
    for (int n = grp * NB; n < grp * NB + NB; ++n) {
        int node = node0 + n;
        if (node >= n_nodes) break;
        float acc = bj;
#pragma unroll
        for (int k = 0; k < K4; ++k) {
            float4 x = X[n * K4 + k];
            acc += wr[k].x * x.x + wr[k].y * x.y + wr[k].z * x.z + wr[k].w * x.w;
        }
        float o = fmaxf(acc, 0.f);
        h_out[(size_t)node * OUT + j] = o;
        sh_out[(size_t)node * OUT + j] = f2bf(o);
    }
}

// ---------------- Set2Set (3 modules batched) ----------------
__device__ __forceinline__ float s2s_hs0(const float* bih, const float* bhh, int m, int d) {
    const float* bi = bih + (size_t)m * 1024;
    const float* bh = bhh + (size_t)m * 1024;
    float gi = bi[d] + bh[d];
    float gg = bi[512 + d] + bh[512 + d];
    float go = bi[768 + d] + bh[768 + d];
    float si = 1.f / (1.f + expf(-gi));
    float so = 1.f / (1.f + expf(-go));
    float c0 = si * tanhf(gg);
    return so * tanhf(c0);
}

// Pass 1: gather h4 rows (scattered), cache as packed bf16, compute r0 (q = hs0).
__global__ __launch_bounds__(256) void attn3_gather(const float* __restrict__ h4,
                                                    const int* __restrict__ path_nodes,
                                                    const float* __restrict__ bih,
                                                    const float* __restrict__ bhh,
                                                    unsigned short* __restrict__ x_cache,
                                                    float* __restrict__ r0_all) {
    int p = blockIdx.x;
    __shared__ float xs[64][256];
    __shared__ float qs[3][256];
    __shared__ float al[3][64];
    __shared__ int nodes[64];
    int tid = threadIdx.x;
    for (int m = 0; m < 3; ++m) qs[m][tid] = s2s_hs0(bih, bhh, m, tid);
    if (tid < 64) nodes[tid] = path_nodes[p * 64 + tid];
    __syncthreads();
    int wv = tid >> 6, ln = tid & 63;
    uint2* xcp = reinterpret_cast<uint2*>(x_cache + (size_t)p * 64 * 256);
    for (int s = wv; s < 64; s += 4) {
        const float4* row = reinterpret_cast<const float4*>(h4 + (size_t)nodes[s] * 256);
        float4 v = row[ln];
        *reinterpret_cast<float4*>(&xs[s][ln * 4]) = v;
        xcp[s * 64 + ln] = bf16_pack(v);
        float d0 = v.x * qs[0][ln * 4] + v.y * qs[0][ln * 4 + 1] +
                   v.z * qs[0][ln * 4 + 2] + v.w * qs[0][ln * 4 + 3];
        float d1 = v.x * qs[1][ln * 4] + v.y * qs[1][ln * 4 + 1] +
                   v.z * qs[1][ln * 4 + 2] + v.w * qs[1][ln * 4 + 3];
        float d2 = v.x * qs[2][ln * 4] + v.y * qs[2][ln * 4 + 1] +
                   v.z * qs[2][ln * 4 + 2] + v.w * qs[2][ln * 4 + 3];
        for (int off = 32; off >= 1; off >>= 1) {
            d0 += __shfl_xor(d0, off, 64);
            d1 += __shfl_xor(d1, off, 64);
            d2 += __shfl_xor(d2, off, 64);
        }
        if (ln == 0) { al[0][s] = d0; al[1][s] = d1; al[2][s] = d2; }
    }
    __syncthreads();
    if (wv < 3) {
        float v = al[wv][ln];
        float mx = v;
        for (int off = 32; off >= 1; off >>= 1) mx = fmaxf(mx, __shfl_xor(mx, off, 64));
        float e = expf(v - mx);
        float sum = e;
        for (int off = 32; off >= 1; off >>= 1) sum += __shfl_xor(sum, off, 64);
        al[wv][ln] = e / sum;
    }
    __syncthreads();
    float a0 = 0.f, a1 = 0.f, a2 = 0.f;
    for (int s = 0; s < 64; ++s) {
        float xv = xs[s][tid];
        a0 += al[0][s] * xv;
        a1 += al[1][s] * xv;
        a2 += al[2][s] * xv;
    }
    r0_all[(size_t)0 * P_PATH * 256 + (size_t)p * 256 + tid] = a0;
    r0_all[(size_t)1 * P_PATH * 256 + (size_t)p * 256 + tid] = a1;
    r0_all[(size_t)2 * P_PATH * 256 + (size_t)p * 256 + tid] = a2;
}

__global__ __launch_bounds__(256) void cpart3(const float* __restrict__ Wih,
                                              const float* __restrict__ Whh,
                                              const float* __restrict__ bih,
                                              const float* __restrict__ bhh,
                                              float* __restrict__ cpart_all) {
    int m = blockIdx.y;
    __shared__ float hss[256];
    int tid = threadIdx.x;
    hss[tid] = s2s_hs0(bih, bhh, m, tid);
    __syncthreads();
    int wv = tid >> 6, ln = tid & 63;
    int j = blockIdx.x * 4 + wv;
    const float4* wi = reinterpret_cast<const float4*>(Wih + (size_t)m * 1024 * 512 + (size_t)j * 512);
    const float4* wh = reinterpret_cast<const float4*>(Whh + (size_t)m * 1024 * 256 + (size_t)j * 256);
    float4 a = wi[ln];
    float4 b = wh[ln];
    float4 h4v = *reinterpret_cast<const float4*>(&hss[ln * 4]);
    float acc = h4v.x * (a.x + b.x) + h4v.y * (a.y + b.y) +
                h4v.z * (a.z + b.z) + h4v.w * (a.w + b.w);
    for (int off = 32; off >= 1; off >>= 1) acc += __shfl_xor(acc, off, 64);
    if (ln == 0)
        cpart_all[m * 1024 + j] = acc + bih[m * 1024 + j] + bhh[m * 1024 + j];
}

__global__ __launch_bounds__(256) void gates_gemm3(const float* __restrict__ r0_all,
                                                   const float* __restrict__ Wih,
                                                   const float* __restrict__ cpart_all,
                                                   float* __restrict__ gates_all) {
    __shared__ float As[64][64];
    __shared__ float Ws[64][64];
    int tid = threadIdx.x;
    int m = blockIdx.z;
    int p0 = blockIdx.x * 64;
    int j0 = blockIdx.y * 64;
    const float* r0 = r0_all + (size_t)m * P_PATH * 256;
    const float* W = Wih + (size_t)m * 1024 * 512;
    int tx = tid & 15, ty = tid >> 4;
    float acc[4][4] = {};
    for (int kc = 0; kc < 256; kc += 64) {
        for (int i = tid; i < 16 * 64; i += 256) {
            int l = i & 63;
            int k4 = i >> 6;
            float4 av = *(reinterpret_cast<const float4*>(r0 + (size_t)(p0 + l) * 256 + kc) + k4);
            As[k4 * 4 + 0][l] = av.x;
            As[k4 * 4 + 1][l] = av.y;
            As[k4 * 4 + 2][l] = av.z;
            As[k4 * 4 + 3][l] = av.w;
            float4 wv = *(reinterpret_cast<const float4*>(W + (size_t)(j0 + l) * 512 + 256 + kc) + k4);
            Ws[k4 * 4 + 0][l] = wv.x;
            Ws[k4 * 4 + 1][l] = wv.y;
            Ws[k4 * 4 + 2][l] = wv.z;
            Ws[k4 * 4 + 3][l] = wv.w;
        }
        __syncthreads();
#pragma unroll 8
        for (int k = 0; k < 64; ++k) {
            float4 a = *reinterpret_cast<const float4*>(&As[k][ty * 4]);
            float4 w = *reinterpret_cast<const float4*>(&Ws[k][tx * 4]);
            acc[0][0] += a.x * w.x; acc[0][1] += a.x * w.y; acc[0][2] += a.x * w.z; acc[0][3] += a.x * w.w;
            acc[1][0] += a.y * w.x; acc[1][1] += a.y * w.y; acc[1][2] += a.y * w.z; acc[1][3] += a.y * w.w;
            acc[2][0] += a.z * w.x; acc[2][1] += a.z * w.y; acc[2][2] += a.z * w.z; acc[2][3] += a.z * w.w;
            acc[3][0] += a.w * w.x; acc[3][1] += a.w * w.y; acc[3][2] += a.w * w.z; acc[3][3] += a.w * w.w;
        }
        __syncthreads();
    }
    float4 cj = *reinterpret_cast<const float4*>(cpart_all + m * 1024 + j0 + tx * 4);
    float* g = gates_all + (size_t)m * P_PATH * 1024;
#pragma unroll
    for (int r = 0; r < 4; ++r) {
        int p = p0 + ty * 4 + r;
        float4 o;
        o.x = acc[r][0] + cj.x;
        o.y = acc[r][1] + cj.y;
        o.z = acc[r][2] + cj.z;
        o.w = acc[r][3] + cj.w;
        *reinterpret_cast<float4*>(g + (size_t)p * 1024 + j0 + tx * 4) = o;
    }
}

// Pass 2: LSTM pointwise fused + attention (q=hs1, bf16 x_cache) + inline xg.
__global__ __launch_bounds__(256) void attn3_linear(const unsigned short* __restrict__ x_cache,
                                                    const float* __restrict__ gates_all,
                                                    const float* __restrict__ bih,
                                                    const float* __restrict__ bhh,
                                                    const float* __restrict__ Wg,
                                                    const float* __restrict__ bg,
                                                    float* __restrict__ xg) {
    int p = blockIdx.x;
    __shared__ float xs[64][256];
    __shared__ float qs[3][256];
    __shared__ float al[3][64];
    __shared__ float wsum[4];
    int tid = threadIdx.x;
    int d = tid;
#pragma unroll
    for (int m = 0; m < 3; ++m) {
        const float* bi = bih + (size_t)m * 1024;
        const float* bh = bhh + (size_t)m * 1024;
        float gi0 = bi[d] + bh[d];
        float gg0 = bi[512 + d] + bh[512 + d];
        float c0 = (1.f / (1.f + expf(-gi0))) * tanhf(gg0);
        const float* g = gates_all + ((size_t)m * P_PATH + p) * 1024;
        float gi = g[d], gf = g[256 + d], gg = g[512 + d], go = g[768 + d];
        float si = 1.f / (1.f + expf(-gi));
        float sf = 1.f / (1.f + expf(-gf));
        float so = 1.f / (1.f + expf(-go));
        float c1 = sf * c0 + si * tanhf(gg);
        qs[m][d] = so * tanhf(c1);
    }
    __syncthreads();
    int wv = tid >> 6, ln = tid & 63;
    const uint2* xcp = reinterpret_cast<const uint2*>(x_cache + (size_t)p * 64 * 256);
    for (int s = wv; s < 64; s += 4) {
        float4 v = bf16_unpack(xcp[s * 64 + ln]);
        *reinterpret_cast<float4*>(&xs[s][ln * 4]) = v;
        float d0 = v.x * qs[0][ln * 4] + v.y * qs[0][ln * 4 + 1] +
                   v.z * qs[0][ln * 4 + 2] + v.w * qs[0][ln * 4 + 3];
        float d1 = v.x * qs[1][ln * 4] + v.y * qs[1][ln * 4 + 1] +
                   v.z * qs[1][ln * 4 + 2] + v.w * qs[1][ln * 4 + 3];
        float d2 = v.x * qs[2][ln * 4] + v.y * qs[2][ln * 4 + 1] +
                   v.z * qs[2][ln * 4 + 2] + v.w * qs[2][ln * 4 + 3];
        for (int off = 32; off >= 1; off >>= 1) {
            d0 += __shfl_xor(d0, off, 64);
            d1 += __shfl_xor(d1, off, 64);
            d2 += __shfl_xor(d2, off, 64);
        }
        if (ln == 0) { al[0][s] = d0; al[1][s] = d1; al[2][s] = d2; }
    }
    __syncthreads();
    if (wv < 3) {
        float v = al[wv][ln];
        float mx = v;
        for (int off = 32; off >= 1; off >>= 1) mx = fmaxf(mx, __shfl_xor(mx, off, 64));
        float e = expf(v - mx);
        float sum = e;
        for (int off = 32; off >= 1; off >>= 1) sum += __shfl_xor(sum, off, 64);
        al[wv][ln] = e / sum;
    }
    __syncthreads();
    float a0 = 0.f, a1 = 0.f, a2 = 0.f;
    for (int s = 0; s < 64; ++s) {
        float xv = xs[s][tid];
        a0 += al[0][s] * xv;
        a1 += al[1][s] * xv;
        a2 += al[2][s] * xv;
    }
    float part = qs[0][tid] * Wg[tid] + a0 * Wg[256 + tid] +
                 qs[1][tid] * Wg[512 + tid] + a1 * Wg[768 + tid] +
                 qs[2][tid] * Wg[1024 + tid] + a2 * Wg[1280 + tid];
    for (int off = 32; off >= 1; off >>= 1) part += __shfl_xor(part, off, 64);
    if (ln == 0) wsum[wv] = part;
    __syncthreads();
    if (tid == 0) xg[p] = wsum[0] + wsum[1] + wsum[2] + wsum[3] + bg[0];
}

// ---------------- head ----------------
__global__ __launch_bounds__(256) void final_mlp(const float* __restrict__ xg,
                                                 const float* __restrict__ Wl1,
                                                 const float* __restrict__ bl1,
                                                 const float* __restrict__ Wl2,
                                                 const float* __restrict__ bl2,
                                                 const float* __restrict__ Wl3,
                                                 const float* __restrict__ bl3,
                                                 float* __restrict__ out) {
    __shared__ float z[512];
    __shared__ float z1[256];
    __shared__ float z2[64];
    int t = threadIdx.x;
    z[t] = xg[t];
    z[256 + t] = xg[256 + t];
    __syncthreads();
    float acc = bl1[t];
    const float* w = Wl1 + (size_t)t * 512;
    for (int k = 0; k < 512; ++k) acc += w[k] * z[k];
    z1[t] = tanhf(acc);
    __syncthreads();
    if (t < 64) {
        float a = bl2[t];
        const float* w2 = Wl2 + (size_t)t * 256;
        for (int k = 0; k < 256; ++k) a += w2[k] * z1[k];
        z2[t] = fmaxf(a, 0.f);
    }
    __syncthreads();
    if (t < 64) {
        float v = Wl3[t] * z2[t];
        for (int off = 32; off >= 1; off >>= 1) v += __shfl_xor(v, off, 64);
        if (t == 0) out[0] = 1.f / (1.f + expf(-(v + bl3[0])));
    }
}

// ---------------- launch ----------------
extern "C" void kernel_launch(void* const* d_in, const int* in_sizes, int n_in,
                              void* d_out, int out_size, void* d_ws, size_t ws_size,
                              hipStream_t stream) {
    const float* h0 = (const float*)d_in[0];
    const int* src = (const int*)d_in[1];
    const int* dst = (const int*)d_in[2];
    const int* path = (const int*)d_in[3];
    const float* W1 = (const float*)d_in[4];
    const float* b1 = (const float*)d_in[5];
    const float* W2 = (const float*)d_in[6];
    const float* b2 = (const float*)d_in[7];
    const float* W3 = (const float*)d_in[8];
    const float* b3 = (const float*)d_in[9];
    const float* W4 = (const float*)d_in[10];
    const float* b4 = (const float*)d_in[11];
    const float* Wih = (const float*)d_in[12];
    const float* Whh = (const float*)d_in[13];
    const float* bih = (const float*)d_in[14];
    const float* bhh = (const float*)d_in[15];
    const float* Wg = (const float*)d_in[16];
    const float* bg = (const float*)d_in[17];
    const float* Wl1 = (const float*)d_in[18];
    const float* bl1 = (const float*)d_in[19];
    const float* Wl2 = (const float*)d_in[20];
    const float* bl2 = (const float*)d_in[21];
    const float* Wl3 = (const float*)d_in[22];
    const float* bl3 = (const float*)d_in[23];

    char* ws = (char*)d_ws;
    int* counts = (int*)(ws + 0);                       // 20000 ints -> 81920
    unsigned short* bins = (unsigned short*)(ws + 81920);  // 20000*96 ushort = 3.84MB -> 3921920
    float* agg = (float*)(ws + 3921920);                // 20000*128 -> 14161920
    float* bufA = (float*)(ws + 14161920);              // 20000*128 -> 24401920
    float* bufB = (float*)(ws + 24401920);              // 20000*256 -> 44881920
    unsigned short* x_cache = (unsigned short*)(ws + 44881920);  // 512*64*256 bf16 = 16.7MB -> 61659136
    unsigned short* shA24 = (unsigned short*)(ws + 61659136);    // 20000*24*2 -> 62619136
    unsigned short* shB64 = (unsigned short*)(ws + 62619136);    // 20000*64*2 -> 65179136
    unsigned short* shA128 = (unsigned short*)(ws + 65179136);   // 20000*128*2 -> 70299136
    float* r0_all = (float*)(ws + 70299136);            // 3*512*256 -> 71872000
    float* gates_all = (float*)(ws + 71872000);         // 3*512*1024 -> 78163456
    float* cpart_all = (float*)(ws + 78163456);         // 3*1024 -> 78175744
    float* xg = (float*)(ws + 78175744);                // 512

    // binned adjacency: zero counts, then single-pass histogram+scatter (ushort bins)
    zero_ints<<<(N_NODES + 255) / 256, 256, 0, stream>>>(counts, N_NODES);
    fill_bins<<<(N_EDGES + 255) / 256, 256, 0, stream>>>(src, dst, counts, bins, N_EDGES);

    // GIN layers (L2-L4 aggs gather bf16 shadows written by the previous linear)
    gin_agg4<<<(N_NODES * 2 + 255) / 256, 256, 0, stream>>>(h0, counts, bins, agg, 2, N_NODES);
    gin_linear_s<8, 24, 8, 16><<<(N_NODES + 127) / 128, 192, 0, stream>>>(h0, agg, W1, b1, bufA, shA24, N_NODES);
    gin_agg4_bf16<<<(N_NODES * 6 + 255) / 256, 256, 0, stream>>>(shA24, counts, bins, agg, 6, N_NODES);
    gin_linear_t<24, 64><<<dim3((N_NODES + 63) / 64, 1), 256, 0, stream>>>(bufA, agg, W2, b2, bufB, shB64, N_NODES);
    gin_agg4_bf16<<<(N_NODES * 16 + 255) / 256, 256, 0, stream>>>(shB64, counts, bins, agg, 16, N_NODES);
    gin_linear_t<64, 128><<<dim3((N_NODES + 63) / 64, 2), 256, 0, stream>>>(bufB, agg, W3, b3, bufA, shA128, N_NODES);
    gin_agg4_bf16<<<(N_NODES * 32 + 255) / 256, 256, 0, stream>>>(shA128, counts, bins, agg, 32, N_NODES);
    gin_linear_128<128, 256><<<dim3((N_NODES + 127) / 128, 4), 256, 0, stream>>>(bufA, agg, W4, b4, bufB, N_NODES);

    const float* h4 = bufB;
    // Set2Set (3 modules batched) + head
    attn3_gather<<<P_PATH, 256, 0, stream>>>(h4, path, bih, bhh, x_cache, r0_all);
    cpart3<<<dim3(256, 3), 256, 0, stream>>>(Wih, Whh, bih, bhh, cpart_all);
    gates_gemm3<<<dim3(8, 16, 3), 256, 0, stream>>>(r0_all, Wih, cpart_all, gates_all);
    attn3_linear<<<P_PATH, 256, 0, stream>>>(x_cache, gates_all, bih, bhh, Wg, bg, xg);
    final_mlp<<<1, 256, 0, stream>>>(xg, Wl1, bl1, Wl2, bl2, Wl3, bl3, (float*)d_out);
}

// Round 16
// 332.355 us; speedup vs baseline: 1.0325x; 1.0325x over previous
//
#include <hip/hip_runtime.h>
#include <hip/hip_bf16.h>
#include <math.h>

#define N_NODES 20000
#define N_EDGES 640000
#define P_PATH 512
#define S_PATH 64
#define BIN_CAP 96  // max in-degree guard; Binomial(640K,1/20K) max ~57 over 20K nodes

static __device__ __forceinline__ unsigned short f2bf(float f) {
    unsigned int b = __float_as_uint(f);
    unsigned int r = (b + 0x7fffu + ((b >> 16) & 1u)) >> 16;
    return (unsigned short)r;
}

// unpack uint2 (4 packed bf16) and accumulate into float4
static __device__ __forceinline__ void bf16_acc(float4& acc, uint2 u) {
    acc.x += __uint_as_float(u.x << 16);
    acc.y += __uint_as_float(u.x & 0xffff0000u);
    acc.z += __uint_as_float(u.y << 16);
    acc.w += __uint_as_float(u.y & 0xffff0000u);
}

// ---------------- binned adjacency build ----------------
__global__ __launch_bounds__(256) void zero_ints(int* p, int n) {
    int i = blockIdx.x * 256 + threadIdx.x;
    if (i < n) p[i] = 0;
}

// single pass: histogram + scatter (atomicAdd returns slot)
__global__ __launch_bounds__(256) void fill_bins(const int* __restrict__ src,
                                                 const int* __restrict__ dst,
                                                 int* __restrict__ counts,
                                                 int* __restrict__ bins, int n) {
    int e = blockIdx.x * 256 + threadIdx.x;
    if (e < n) {
        int node = dst[e];
        int pos = atomicAdd(&counts[node], 1);
        if (pos < BIN_CAP) bins[node * BIN_CAP + pos] = src[e];
    }
}

// ---------------- GIN aggregation ----------------
// fp32 variant (layer 1 reads input h0)
__global__ __launch_bounds__(256) void gin_agg4(const float* __restrict__ h_in,
                                                const int* __restrict__ counts,
                                                const int* __restrict__ bins,
                                                float* __restrict__ agg, int dim4, int n_nodes) {
    int id = blockIdx.x * 256 + threadIdx.x;
    if (id >= n_nodes * dim4) return;
    int node = id / dim4;
    int d4 = id - node * dim4;
    int cnt = counts[node];
    if (cnt > BIN_CAP) cnt = BIN_CAP;
    const int* bp = bins + node * BIN_CAP;
    const float4* hp = reinterpret_cast<const float4*>(h_in);
    float4 a0 = {0,0,0,0}, a1 = {0,0,0,0}, a2 = {0,0,0,0}, a3 = {0,0,0,0};
    float4 a4 = {0,0,0,0}, a5 = {0,0,0,0}, a6 = {0,0,0,0}, a7 = {0,0,0,0};
    int e = 0;
    for (; e + 8 <= cnt; e += 8) {
        int s0 = bp[e + 0], s1 = bp[e + 1], s2 = bp[e + 2], s3 = bp[e + 3];
        int s4 = bp[e + 4], s5 = bp[e + 5], s6 = bp[e + 6], s7 = bp[e + 7];
        float4 v0 = hp[(size_t)s0 * dim4 + d4];
        float4 v1 = hp[(size_t)s1 * dim4 + d4];
        float4 v2 = hp[(size_t)s2 * dim4 + d4];
        float4 v3 = hp[(size_t)s3 * dim4 + d4];
        float4 v4 = hp[(size_t)s4 * dim4 + d4];
        float4 v5 = hp[(size_t)s5 * dim4 + d4];
        float4 v6 = hp[(size_t)s6 * dim4 + d4];
        float4 v7 = hp[(size_t)s7 * dim4 + d4];
        a0.x += v0.x; a0.y += v0.y; a0.z += v0.z; a0.w += v0.w;
        a1.x += v1.x; a1.y += v1.y; a1.z += v1.z; a1.w += v1.w;
        a2.x += v2.x; a2.y += v2.y; a2.z += v2.z; a2.w += v2.w;
        a3.x += v3.x; a3.y += v3.y; a3.z += v3.z; a3.w += v3.w;
        a4.x += v4.x; a4.y += v4.y; a4.z += v4.z; a4.w += v4.w;
        a5.x += v5.x; a5.y += v5.y; a5.z += v5.z; a5.w += v5.w;
        a6.x += v6.x; a6.y += v6.y; a6.z += v6.z; a6.w += v6.w;
        a7.x += v7.x; a7.y += v7.y; a7.z += v7.z; a7.w += v7.w;
    }
    for (; e < cnt; ++e) {
        float4 v = hp[(size_t)bp[e] * dim4 + d4];
        a0.x += v.x; a0.y += v.y; a0.z += v.z; a0.w += v.w;
    }
    float4 r;
    r.x = (a0.x + a1.x) + (a2.x + a3.x) + (a4.x + a5.x) + (a6.x + a7.x);
    r.y = (a0.y + a1.y) + (a2.y + a3.y) + (a4.y + a5.y) + (a6.y + a7.y);
    r.z = (a0.z + a1.z) + (a2.z + a3.z) + (a4.z + a5.z) + (a6.z + a7.z);
    r.w = (a0.w + a1.w) + (a2.w + a3.w) + (a4.w + a5.w) + (a6.w + a7.w);
    reinterpret_cast<float4*>(agg)[id] = r;
}

// bf16-shadow variant (layers 2-4): halves gather bytes; fp32 accumulate.
__global__ __launch_bounds__(256) void gin_agg4_bf16(const unsigned short* __restrict__ hb,
                                                     const int* __restrict__ counts,
                                                     const int* __restrict__ bins,
                                                     float* __restrict__ agg, int dim4,
                                                     int n_nodes) {
    int id = blockIdx.x * 256 + threadIdx.x;
    if (id >= n_nodes * dim4) return;
    int node = id / dim4;
    int d4 = id - node * dim4;
    int cnt = counts[node];
    if (cnt > BIN_CAP) cnt = BIN_CAP;
    const int* bp = bins + node * BIN_CAP;
    const uint2* hp = reinterpret_cast<const uint2*>(hb);  // one uint2 = 4 bf16
    float4 a0 = {0,0,0,0}, a1 = {0,0,0,0}, a2 = {0,0,0,0}, a3 = {0,0,0,0};
    float4 a4 = {0,0,0,0}, a5 = {0,0,0,0}, a6 = {0,0,0,0}, a7 = {0,0,0,0};
    int e = 0;
    for (; e + 8 <= cnt; e += 8) {
        int s0 = bp[e + 0], s1 = bp[e + 1], s2 = bp[e + 2], s3 = bp[e + 3];
        int s4 = bp[e + 4], s5 = bp[e + 5], s6 = bp[e + 6], s7 = bp[e + 7];
        uint2 u0 = hp[(size_t)s0 * dim4 + d4];
        uint2 u1 = hp[(size_t)s1 * dim4 + d4];
        uint2 u2 = hp[(size_t)s2 * dim4 + d4];
        uint2 u3 = hp[(size_t)s3 * dim4 + d4];
        uint2 u4 = hp[(size_t)s4 * dim4 + d4];
        uint2 u5 = hp[(size_t)s5 * dim4 + d4];
        uint2 u6 = hp[(size_t)s6 * dim4 + d4];
        uint2 u7 = hp[(size_t)s7 * dim4 + d4];
        bf16_acc(a0, u0); bf16_acc(a1, u1); bf16_acc(a2, u2); bf16_acc(a3, u3);
        bf16_acc(a4, u4); bf16_acc(a5, u5); bf16_acc(a6, u6); bf16_acc(a7, u7);
    }
    for (; e < cnt; ++e) {
        uint2 u = hp[(size_t)bp[e] * dim4 + d4];
        bf16_acc(a0, u);
    }
    float4 r;
    r.x = (a0.x + a1.x) + (a2.x + a3.x) + (a4.x + a5.x) + (a6.x + a7.x);
    r.y = (a0.y + a1.y) + (a2.y + a3.y) + (a4.y + a5.y) + (a6.y + a7.y);
    r.z = (a0.z + a1.z) + (a2.z + a3.z) + (a4.z + a5.z) + (a6.z + a7.z);
    r.w = (a0.w + a1.w) + (a2.w + a3.w) + (a4.w + a5.w) + (a6.w + a7.w);
    reinterpret_cast<float4*>(agg)[id] = r;
}

// Register-tiled fp32 GEMM, 64n x 64j tile; also writes bf16 shadow of output.
template <int IN, int OUT>
__global__ __launch_bounds__(256) void gin_linear_t(const float* __restrict__ h_in,
                                                    const float* __restrict__ agg,
                                                    const float* __restrict__ W,
                                                    const float* __restrict__ b,
                                                    float* __restrict__ h_out,
                                                    unsigned short* __restrict__ sh_out,
                                                    int n_nodes) {
    constexpr int KC = (IN >= 64) ? 64 : IN;
    constexpr int KC4 = KC / 4;
    __shared__ float Xs[KC][64];
    __shared__ float Ws[KC][64];
    int tid = threadIdx.x;
    int node0 = blockIdx.x * 64;
    int j0 = blockIdx.y * 64;
    int tx = tid & 15, ty = tid >> 4;
    float acc[4][4] = {};
    for (int kc = 0; kc < IN; kc += KC) {
        for (int i = tid; i < KC4 * 64; i += 256) {
            int l = i & 63;
            int k4 = i >> 6;
            int node = node0 + l;
            float4 v = {0.f, 0.f, 0.f, 0.f};
            if (node < n_nodes) {
                const float4* hp =
                    reinterpret_cast<const float4*>(h_in + (size_t)node * IN + kc) + k4;
                const float4* ap =
                    reinterpret_cast<const float4*>(agg + (size_t)node * IN + kc) + k4;
                float4 a = *hp, g = *ap;
                v.x = a.x + g.x; v.y = a.y + g.y; v.z = a.z + g.z; v.w = a.w + g.w;
            }
            Xs[k4 * 4 + 0][l] = v.x;
            Xs[k4 * 4 + 1][l] = v.y;
            Xs[k4 * 4 + 2][l] = v.z;
            Xs[k4 * 4 + 3][l] = v.w;
            float4 wv = *(reinterpret_cast<const float4*>(W + (size_t)(j0 + l) * IN + kc) + k4);
            Ws[k4 * 4 + 0][l] = wv.x;
            Ws[k4 * 4 + 1][l] = wv.y;
            Ws[k4 * 4 + 2][l] = wv.z;
            Ws[k4 * 4 + 3][l] = wv.w;
        }
        __syncthreads();
#pragma unroll 8
        for (int k = 0; k < KC; ++k) {
            float4 a = *reinterpret_cast<const float4*>(&Xs[k][ty * 4]);
            float4 w = *reinterpret_cast<const float4*>(&Ws[k][tx * 4]);
            acc[0][0] += a.x * w.x; acc[0][1] += a.x * w.y; acc[0][2] += a.x * w.z; acc[0][3] += a.x * w.w;
            acc[1][0] += a.y * w.x; acc[1][1] += a.y * w.y; acc[1][2] += a.y * w.z; acc[1][3] += a.y * w.w;
            acc[2][0] += a.z * w.x; acc[2][1] += a.z * w.y; acc[2][2] += a.z * w.z; acc[2][3] += a.z * w.w;
            acc[3][0] += a.w * w.x; acc[3][1] += a.w * w.y; acc[3][2] += a.w * w.z; acc[3][3] += a.w * w.w;
        }
        __syncthreads();
    }
    float4 bj = *reinterpret_cast<const float4*>(b + j0 + tx * 4);
#pragma unroll
    for (int r = 0; r < 4; ++r) {
        int node = node0 + ty * 4 + r;
        if (node < n_nodes) {
            float4 o;
            o.x = fmaxf(acc[r][0] + bj.x, 0.f);
            o.y = fmaxf(acc[r][1] + bj.y, 0.f);
            o.z = fmaxf(acc[r][2] + bj.z, 0.f);
            o.w = fmaxf(acc[r][3] + bj.w, 0.f);
            *reinterpret_cast<float4*>(h_out + (size_t)node * OUT + j0 + tx * 4) = o;
            ushort4 us;
            us.x = f2bf(o.x); us.y = f2bf(o.y); us.z = f2bf(o.z); us.w = f2bf(o.w);
            *reinterpret_cast<ushort4*>(sh_out + (size_t)node * OUT + j0 + tx * 4) = us;
        }
    }
}

// 128-node x 64-j tile for L4 (IN=128): no shadow (attn reads fp32 h4).
template <int IN, int OUT>
__global__ __launch_bounds__(256) void gin_linear_128(const float* __restrict__ h_in,
                                                      const float* __restrict__ agg,
                                                      const float* __restrict__ W,
                                                      const float* __restrict__ b,
                                                      float* __restrict__ h_out, int n_nodes) {
    constexpr int KC = 32, KC4 = 8;
    constexpr int XSS = 132;
    constexpr int WSS = 68;
    __shared__ float Xs[KC * XSS];
    __shared__ float Ws[KC * WSS];
    int tid = threadIdx.x;
    int node0 = blockIdx.x * 128;
    int j0 = blockIdx.y * 64;
    int tx = tid & 15, ty = tid >> 4;
    float acc[8][4] = {};
    for (int kc = 0; kc < IN; kc += KC) {
        for (int i = tid; i < 128 * KC4; i += 256) {
            int node_l = i >> 3;
            int k4 = i & 7;
            int node = node0 + node_l;
            float4 v = {0.f, 0.f, 0.f, 0.f};
            if (node < n_nodes) {
                float4 a = *(reinterpret_cast<const float4*>(h_in + (size_t)node * IN + kc) + k4);
                float4 g = *(reinterpret_cast<const float4*>(agg + (size_t)node * IN + kc) + k4);
                v.x = a.x + g.x; v.y = a.y + g.y; v.z = a.z + g.z; v.w = a.w + g.w;
            }
            Xs[(k4 * 4 + 0) * XSS + node_l] = v.x;
            Xs[(k4 * 4 + 1) * XSS + node_l] = v.y;
            Xs[(k4 * 4 + 2) * XSS + node_l] = v.z;
            Xs[(k4 * 4 + 3) * XSS + node_l] = v.w;
        }
        for (int i = tid; i < 64 * KC4; i += 256) {
            int jl = i >> 3;
            int k4 = i & 7;
            float4 wv = *(reinterpret_cast<const float4*>(W + (size_t)(j0 + jl) * IN + kc) + k4);
            Ws[(k4 * 4 + 0) * WSS + jl] = wv.x;
            Ws[(k4 * 4 + 1) * WSS + jl] = wv.y;
            Ws[(k4 * 4 + 2) * WSS + jl] = wv.z;
            Ws[(k4 * 4 + 3) * WSS + jl] = wv.w;
        }
        __syncthreads();
#pragma unroll 8
        for (int k = 0; k < KC; ++k) {
            float4 a0 = *reinterpret_cast<const float4*>(&Xs[k * XSS + ty * 8]);
            float4 a1 = *reinterpret_cast<const float4*>(&Xs[k * XSS + ty * 8 + 4]);
            float4 w = *reinterpret_cast<const float4*>(&Ws[k * WSS + tx * 4]);
            acc[0][0] += a0.x * w.x; acc[0][1] += a0.x * w.y; acc[0][2] += a0.x * w.z; acc[0][3] += a0.x * w.w;
            acc[1][0] += a0.y * w.x; acc[1][1] += a0.y * w.y; acc[1][2] += a0.y * w.z; acc[1][3] += a0.y * w.w;
            acc[2][0] += a0.z * w.x; acc[2][1] += a0.z * w.y; acc[2][2] += a0.z * w.z; acc[2][3] += a0.z * w.w;
            acc[3][0] += a0.w * w.x; acc[3][1] += a0.w * w.y; acc[3][2] += a0.w * w.z; acc[3][3] += a0.w * w.w;
            acc[4][0] += a1.x * w.x; acc[4][1] += a1.x * w.y; acc[4][2] += a1.x * w.z; acc[4][3] += a1.x * w.w;
            acc[5][0] += a1.y * w.x; acc[5][1] += a1.y * w.y; acc[5][2] += a1.y * w.z; acc[5][3] += a1.y * w.w;
            acc[6][0] += a1.z * w.x; acc[6][1] += a1.z * w.y; acc[6][2] += a1.z * w.z; acc[6][3] += a1.z * w.w;
            acc[7][0] += a1.w * w.x; acc[7][1] += a1.w * w.y; acc[7][2] += a1.w * w.z; acc[7][3] += a1.w * w.w;
        }
        __syncthreads();
    }
    float4 bj = *reinterpret_cast<const float4*>(b + j0 + tx * 4);
#pragma unroll
    for (int r = 0; r < 8; ++r) {
        int node = node0 + ty * 8 + r;
        if (node < n_nodes) {
            float4 o;
            o.x = fmaxf(acc[r][0] + bj.x, 0.f);
            o.y = fmaxf(acc[r][1] + bj.y, 0.f);
            o.z = fmaxf(acc[r][2] + bj.z, 0.f);
            o.w = fmaxf(acc[r][3] + bj.w, 0.f);
            *reinterpret_cast<float4*>(h_out + (size_t)node * OUT + j0 + tx * 4) = o;
        }
    }
}

// layer-1 (IN=8) small kernel; writes fp32 + bf16 shadow
template <int IN, int OUT, int NG, int NB>
__global__ __launch_bounds__(OUT * NG) void gin_linear_s(const float* __restrict__ h_in,
                                                         const float* __restrict__ agg,
                                                         const float* __restrict__ W,
                                                         const float* __restrict__ b,
                                                         float* __restrict__ h_out,
                                                         unsigned short* __restrict__ sh_out,
                                                         int n_nodes) {
    constexpr int NODES = NG * NB;
    constexpr int K4 = IN / 4;
    __shared__ float4 X[NODES * K4];
    int tid = threadIdx.x;
    int node0 = blockIdx.x * NODES;
    const float4* hp = reinterpret_cast<const float4*>(h_in);
    const float4* ap = reinterpret_cast<const float4*>(agg);
    for (int i = tid; i < NODES * K4; i += OUT * NG) {
        int node = node0 + i / K4;
        float4 v = {0.f, 0.f, 0.f, 0.f};
        if (node < n_nodes) {
            size_t idx = (size_t)node0 * K4 + i;
            float4 a = hp[idx], g = ap[idx];
            v.x = a.x + g.x; v.y = a.y + g.y; v.z = a.z + g.z; v.w = a.w + g.w;
        }
        X[i] = v;
    }
    __syncthreads();
    int grp = tid / OUT, j = tid - grp * OUT;
    float4 wr[K4];
    const float4* Wp = reinterpret_cast<const float4*>(W + (size_t)j * IN);
#pragma unroll
    for (int k = 0; k < K4; ++k) wr[k] = Wp[k];
    float bj = b[j];
    for (int n = grp * NB; n < grp * NB + NB; ++n) {
        int node = node0 + n;
        if (node >= n_nodes) break;
        float acc = bj;
#pragma unroll
        for (int k = 0; k < K4; ++k) {
            float4 x = X[n * K4 + k];
            acc += wr[k].x * x.x + wr[k].y * x.y + wr[k].z * x.z + wr[k].w * x.w;
        }
        float o = fmaxf(acc, 0.f);
        h_out[(size_t)node * OUT + j] = o;
        sh_out[(size_t)node * OUT + j] = f2bf(o);
    }
}

// ---------------- Set2Set (3 modules batched) ----------------
__device__ __forceinline__ float s2s_hs0(const float* bih, const float* bhh, int m, int d) {
    const float* bi = bih + (size_t)m * 1024;
    const float* bh = bhh + (size_t)m * 1024;
    float gi = bi[d] + bh[d];
    float gg = bi[512 + d] + bh[512 + d];
    float go = bi[768 + d] + bh[768 + d];
    float si = 1.f / (1.f + expf(-gi));
    float so = 1.f / (1.f + expf(-go));
    float c0 = si * tanhf(gg);
    return so * tanhf(c0);
}

__global__ __launch_bounds__(256) void attn3_gather(const float* __restrict__ h4,
                                                    const int* __restrict__ path_nodes,
                                                    const float* __restrict__ bih,
                                                    const float* __restrict__ bhh,
                                                    float* __restrict__ x_cache,
                                                    float* __restrict__ r0_all) {
    int p = blockIdx.x;
    __shared__ float xs[64][256];
    __shared__ float qs[3][256];
    __shared__ float al[3][64];
    __shared__ int nodes[64];
    int tid = threadIdx.x;
    for (int m = 0; m < 3; ++m) qs[m][tid] = s2s_hs0(bih, bhh, m, tid);
    if (tid < 64) nodes[tid] = path_nodes[p * 64 + tid];
    __syncthreads();
    int wv = tid >> 6, ln = tid & 63;
    float4* xcp = reinterpret_cast<float4*>(x_cache + (size_t)p * 64 * 256);
    for (int s = wv; s < 64; s += 4) {
        const float4* row = reinterpret_cast<const float4*>(h4 + (size_t)nodes[s] * 256);
        float4 v = row[ln];
        *reinterpret_cast<float4*>(&xs[s][ln * 4]) = v;
        xcp[s * 64 + ln] = v;
        float d0 = v.x * qs[0][ln * 4] + v.y * qs[0][ln * 4 + 1] +
                   v.z * qs[0][ln * 4 + 2] + v.w * qs[0][ln * 4 + 3];
        float d1 = v.x * qs[1][ln * 4] + v.y * qs[1][ln * 4 + 1] +
                   v.z * qs[1][ln * 4 + 2] + v.w * qs[1][ln * 4 + 3];
        float d2 = v.x * qs[2][ln * 4] + v.y * qs[2][ln * 4 + 1] +
                   v.z * qs[2][ln * 4 + 2] + v.w * qs[2][ln * 4 + 3];
        for (int off = 32; off >= 1; off >>= 1) {
            d0 += __shfl_xor(d0, off, 64);
            d1 += __shfl_xor(d1, off, 64);
            d2 += __shfl_xor(d2, off, 64);
        }
        if (ln == 0) { al[0][s] = d0; al[1][s] = d1; al[2][s] = d2; }
    }
    __syncthreads();
    if (wv < 3) {
        float v = al[wv][ln];
        float mx = v;
        for (int off = 32; off >= 1; off >>= 1) mx = fmaxf(mx, __shfl_xor(mx, off, 64));
        float e = expf(v - mx);
        float sum = e;
        for (int off = 32; off >= 1; off >>= 1) sum += __shfl_xor(sum, off, 64);
        al[wv][ln] = e / sum;
    }
    __syncthreads();
    float a0 = 0.f, a1 = 0.f, a2 = 0.f;
    for (int s = 0; s < 64; ++s) {
        float xv = xs[s][tid];
        a0 += al[0][s] * xv;
        a1 += al[1][s] * xv;
        a2 += al[2][s] * xv;
    }
    r0_all[(size_t)0 * P_PATH * 256 + (size_t)p * 256 + tid] = a0;
    r0_all[(size_t)1 * P_PATH * 256 + (size_t)p * 256 + tid] = a1;
    r0_all[(size_t)2 * P_PATH * 256 + (size_t)p * 256 + tid] = a2;
}

__global__ __launch_bounds__(256) void cpart3(const float* __restrict__ Wih,
                                              const float* __restrict__ Whh,
                                              const float* __restrict__ bih,
                                              const float* __restrict__ bhh,
                                              float* __restrict__ cpart_all) {
    int m = blockIdx.y;
    __shared__ float hss[256];
    int tid = threadIdx.x;
    hss[tid] = s2s_hs0(bih, bhh, m, tid);
    __syncthreads();
    int wv = tid >> 6, ln = tid & 63;
    int j = blockIdx.x * 4 + wv;
    const float4* wi = reinterpret_cast<const float4*>(Wih + (size_t)m * 1024 * 512 + (size_t)j * 512);
    const float4* wh = reinterpret_cast<const float4*>(Whh + (size_t)m * 1024 * 256 + (size_t)j * 256);
    float4 a = wi[ln];
    float4 b = wh[ln];
    float4 h4v = *reinterpret_cast<const float4*>(&hss[ln * 4]);
    float acc = h4v.x * (a.x + b.x) + h4v.y * (a.y + b.y) +
                h4v.z * (a.z + b.z) + h4v.w * (a.w + b.w);
    for (int off = 32; off >= 1; off >>= 1) acc += __shfl_xor(acc, off, 64);
    if (ln == 0)
        cpart_all[m * 1024 + j] = acc + bih[m * 1024 + j] + bhh[m * 1024 + j];
}

__global__ __launch_bounds__(256) void gates_gemm3(const float* __restrict__ r0_all,
                                                   const float* __restrict__ Wih,
                                                   const float* __restrict__ cpart_all,
                                                   float* __restrict__ gates_all) {
    __shared__ float As[64][64];
    __shared__ float Ws[64][64];
    int tid = threadIdx.x;
    int m = blockIdx.z;
    int p0 = blockIdx.x * 64;
    int j0 = blockIdx.y * 64;
    const float* r0 = r0_all + (size_t)m * P_PATH * 256;
    const float* W = Wih + (size_t)m * 1024 * 512;
    int tx = tid & 15, ty = tid >> 4;
    float acc[4][4] = {};
    for (int kc = 0; kc < 256; kc += 64) {
        for (int i = tid; i < 16 * 64; i += 256) {
            int l = i & 63;
            int k4 = i >> 6;
            float4 av = *(reinterpret_cast<const float4*>(r0 + (size_t)(p0 + l) * 256 + kc) + k4);
            As[k4 * 4 + 0][l] = av.x;
            As[k4 * 4 + 1][l] = av.y;
            As[k4 * 4 + 2][l] = av.z;
            As[k4 * 4 + 3][l] = av.w;
            float4 wv = *(reinterpret_cast<const float4*>(W + (size_t)(j0 + l) * 512 + 256 + kc) + k4);
            Ws[k4 * 4 + 0][l] = wv.x;
            Ws[k4 * 4 + 1][l] = wv.y;
            Ws[k4 * 4 + 2][l] = wv.z;
            Ws[k4 * 4 + 3][l] = wv.w;
        }
        __syncthreads();
#pragma unroll 8
        for (int k = 0; k < 64; ++k) {
            float4 a = *reinterpret_cast<const float4*>(&As[k][ty * 4]);
            float4 w = *reinterpret_cast<const float4*>(&Ws[k][tx * 4]);
            acc[0][0] += a.x * w.x; acc[0][1] += a.x * w.y; acc[0][2] += a.x * w.z; acc[0][3] += a.x * w.w;
            acc[1][0] += a.y * w.x; acc[1][1] += a.y * w.y; acc[1][2] += a.y * w.z; acc[1][3] += a.y * w.w;
            acc[2][0] += a.z * w.x; acc[2][1] += a.z * w.y; acc[2][2] += a.z * w.z; acc[2][3] += a.z * w.w;
            acc[3][0] += a.w * w.x; acc[3][1] += a.w * w.y; acc[3][2] += a.w * w.z; acc[3][3] += a.w * w.w;
        }
        __syncthreads();
    }
    float4 cj = *reinterpret_cast<const float4*>(cpart_all + m * 1024 + j0 + tx * 4);
    float* g = gates_all + (size_t)m * P_PATH * 1024;
#pragma unroll
    for (int r = 0; r < 4; ++r) {
        int p = p0 + ty * 4 + r;
        float4 o;
        o.x = acc[r][0] + cj.x;
        o.y = acc[r][1] + cj.y;
        o.z = acc[r][2] + cj.z;
        o.w = acc[r][3] + cj.w;
        *reinterpret_cast<float4*>(g + (size_t)p * 1024 + j0 + tx * 4) = o;
    }
}

// Pass 2: LSTM pointwise fused + attention (q=hs1, linear x_cache) + inline xg.
__global__ __launch_bounds__(256) void attn3_linear(const float* __restrict__ x_cache,
                                                    const float* __restrict__ gates_all,
                                                    const float* __restrict__ bih,
                                                    const float* __restrict__ bhh,
                                                    const float* __restrict__ Wg,
                                                    const float* __restrict__ bg,
                                                    float* __restrict__ xg) {
    int p = blockIdx.x;
    __shared__ float xs[64][256];
    __shared__ float qs[3][256];
    __shared__ float al[3][64];
    __shared__ float wsum[4];
    int tid = threadIdx.x;
    int d = tid;
#pragma unroll
    for (int m = 0; m < 3; ++m) {
        const float* bi = bih + (size_t)m * 1024;
        const float* bh = bhh + (size_t)m * 1024;
        float gi0 = bi[d] + bh[d];
        float gg0 = bi[512 + d] + bh[512 + d];
        float c0 = (1.f / (1.f + expf(-gi0))) * tanhf(gg0);
        const float* g = gates_all + ((size_t)m * P_PATH + p) * 1024;
        float gi = g[d], gf = g[256 + d], gg = g[512 + d], go = g[768 + d];
        float si = 1.f / (1.f + expf(-gi));
        float sf = 1.f / (1.f + expf(-gf));
        float so = 1.f / (1.f + expf(-go));
        float c1 = sf * c0 + si * tanhf(gg);
        qs[m][d] = so * tanhf(c1);
    }
    __syncthreads();
    int wv = tid >> 6, ln = tid & 63;
    const float4* xcp = reinterpret_cast<const float4*>(x_cache + (size_t)p * 64 * 256);
    for (int s = wv; s < 64; s += 4) {
        float4 v = xcp[s * 64 + ln];
        *reinterpret_cast<float4*>(&xs[s][ln * 4]) = v;
        float d0 = v.x * qs[0][ln * 4] + v.y * qs[0][ln * 4 + 1] +
                   v.z * qs[0][ln * 4 + 2] + v.w * qs[0][ln * 4 + 3];
        float d1 = v.x * qs[1][ln * 4] + v.y * qs[1][ln * 4 + 1] +
                   v.z * qs[1][ln * 4 + 2] + v.w * qs[1][ln * 4 + 3];
        float d2 = v.x * qs[2][ln * 4] + v.y * qs[2][ln * 4 + 1] +
                   v.z * qs[2][ln * 4 + 2] + v.w * qs[2][ln * 4 + 3];
        for (int off = 32; off >= 1; off >>= 1) {
            d0 += __shfl_xor(d0, off, 64);
            d1 += __shfl_xor(d1, off, 64);
            d2 += __shfl_xor(d2, off, 64);
        }
        if (ln == 0) { al[0][s] = d0; al[1][s] = d1; al[2][s] = d2; }
    }
    __syncthreads();
    if (wv < 3) {
        float v = al[wv][ln];
        float mx = v;
        for (int off = 32; off >= 1; off >>= 1) mx = fmaxf(mx, __shfl_xor(mx, off, 64));
        float e = expf(v - mx);
        float sum = e;
        for (int off = 32; off >= 1; off >>= 1) sum += __shfl_xor(sum, off, 64);
        al[wv][ln] = e / sum;
    }
    __syncthreads();
    float a0 = 0.f, a1 = 0.f, a2 = 0.f;
    for (int s = 0; s < 64; ++s) {
        float xv = xs[s][tid];
        a0 += al[0][s] * xv;
        a1 += al[1][s] * xv;
        a2 += al[2][s] * xv;
    }
    float part = qs[0][tid] * Wg[tid] + a0 * Wg[256 + tid] +
                 qs[1][tid] * Wg[512 + tid] + a1 * Wg[768 + tid] +
                 qs[2][tid] * Wg[1024 + tid] + a2 * Wg[1280 + tid];
    for (int off = 32; off >= 1; off >>= 1) part += __shfl_xor(part, off, 64);
    if (ln == 0) wsum[wv] = part;
    __syncthreads();
    if (tid == 0) xg[p] = wsum[0] + wsum[1] + wsum[2] + wsum[3] + bg[0];
}

// ---------------- head ----------------
__global__ __launch_bounds__(256) void final_mlp(const float* __restrict__ xg,
                                                 const float* __restrict__ Wl1,
                                                 const float* __restrict__ bl1,
                                                 const float* __restrict__ Wl2,
                                                 const float* __restrict__ bl2,
                                                 const float* __restrict__ Wl3,
                                                 const float* __restrict__ bl3,
                                                 float* __restrict__ out) {
    __shared__ float z[512];
    __shared__ float z1[256];
    __shared__ float z2[64];
    int t = threadIdx.x;
    z[t] = xg[t];
    z[256 + t] = xg[256 + t];
    __syncthreads();
    float acc = bl1[t];
    const float* w = Wl1 + (size_t)t * 512;
    for (int k = 0; k < 512; ++k) acc += w[k] * z[k];
    z1[t] = tanhf(acc);
    __syncthreads();
    if (t < 64) {
        float a = bl2[t];
        const float* w2 = Wl2 + (size_t)t * 256;
        for (int k = 0; k < 256; ++k) a += w2[k] * z1[k];
        z2[t] = fmaxf(a, 0.f);
    }
    __syncthreads();
    if (t < 64) {
        float v = Wl3[t] * z2[t];
        for (int off = 32; off >= 1; off >>= 1) v += __shfl_xor(v, off, 64);
        if (t == 0) out[0] = 1.f / (1.f + expf(-(v + bl3[0])));
    }
}

// ---------------- launch ----------------
extern "C" void kernel_launch(void* const* d_in, const int* in_sizes, int n_in,
                              void* d_out, int out_size, void* d_ws, size_t ws_size,
                              hipStream_t stream) {
    const float* h0 = (const float*)d_in[0];
    const int* src = (const int*)d_in[1];
    const int* dst = (const int*)d_in[2];
    const int* path = (const int*)d_in[3];
    const float* W1 = (const float*)d_in[4];
    const float* b1 = (const float*)d_in[5];
    const float* W2 = (const float*)d_in[6];
    const float* b2 = (const float*)d_in[7];
    const float* W3 = (const float*)d_in[8];
    const float* b3 = (const float*)d_in[9];
    const float* W4 = (const float*)d_in[10];
    const float* b4 = (const float*)d_in[11];
    const float* Wih = (const float*)d_in[12];
    const float* Whh = (const float*)d_in[13];
    const float* bih = (const float*)d_in[14];
    const float* bhh = (const float*)d_in[15];
    const float* Wg = (const float*)d_in[16];
    const float* bg = (const float*)d_in[17];
    const float* Wl1 = (const float*)d_in[18];
    const float* bl1 = (const float*)d_in[19];
    const float* Wl2 = (const float*)d_in[20];
    const float* bl2 = (const float*)d_in[21];
    const float* Wl3 = (const float*)d_in[22];
    const float* bl3 = (const float*)d_in[23];

    char* ws = (char*)d_ws;
    int* counts = (int*)(ws + 0);                // 20000 ints -> 81920
    int* bins = (int*)(ws + 81920);              // 20000*96 ints -> 7761920
    float* agg = (float*)(ws + 7761920);         // 20000*128 -> 18001920
    float* bufA = (float*)(ws + 18001920);       // 20000*128 -> 28241920
    float* bufB = (float*)(ws + 28241920);       // 20000*256 -> 48721920
    float* x_cache = (float*)(ws + 48721920);    // 512*64*256 -> 82276352
    // bf16 shadows overlap x_cache (dead during GIN phase):
    unsigned short* shA24 = (unsigned short*)(ws + 48721920);   // 20000*24*2
    unsigned short* shB64 = (unsigned short*)(ws + 49681920);   // 20000*64*2
    unsigned short* shA128 = (unsigned short*)(ws + 52241920);  // 20000*128*2
    float* r0_all = (float*)(ws + 82276352);     // 3*512*256 -> 83849216
    float* gates_all = (float*)(ws + 83849216);  // 3*512*1024 -> 90140672
    float* cpart_all = (float*)(ws + 90140672);  // 3*1024 -> 90152960
    float* xg = (float*)(ws + 90152960);         // 512

    // binned adjacency: zero counts, then single-pass histogram+scatter
    zero_ints<<<(N_NODES + 255) / 256, 256, 0, stream>>>(counts, N_NODES);
    fill_bins<<<(N_EDGES + 255) / 256, 256, 0, stream>>>(src, dst, counts, bins, N_EDGES);

    // GIN layers (L2-L4 aggs gather bf16 shadows written by the previous linear)
    gin_agg4<<<(N_NODES * 2 + 255) / 256, 256, 0, stream>>>(h0, counts, bins, agg, 2, N_NODES);
    gin_linear_s<8, 24, 8, 16><<<(N_NODES + 127) / 128, 192, 0, stream>>>(h0, agg, W1, b1, bufA, shA24, N_NODES);
    gin_agg4_bf16<<<(N_NODES * 6 + 255) / 256, 256, 0, stream>>>(shA24, counts, bins, agg, 6, N_NODES);
    gin_linear_t<24, 64><<<dim3((N_NODES + 63) / 64, 1), 256, 0, stream>>>(bufA, agg, W2, b2, bufB, shB64, N_NODES);
    gin_agg4_bf16<<<(N_NODES * 16 + 255) / 256, 256, 0, stream>>>(shB64, counts, bins, agg, 16, N_NODES);
    gin_linear_t<64, 128><<<dim3((N_NODES + 63) / 64, 2), 256, 0, stream>>>(bufB, agg, W3, b3, bufA, shA128, N_NODES);
    gin_agg4_bf16<<<(N_NODES * 32 + 255) / 256, 256, 0, stream>>>(shA128, counts, bins, agg, 32, N_NODES);
    gin_linear_128<128, 256><<<dim3((N_NODES + 127) / 128, 4), 256, 0, stream>>>(bufA, agg, W4, b4, bufB, N_NODES);

    const float* h4 = bufB;
    // Set2Set (3 modules batched) + head
    attn3_gather<<<P_PATH, 256, 0, stream>>>(h4, path, bih, bhh, x_cache, r0_all);
    cpart3<<<dim3(256, 3), 256, 0, stream>>>(Wih, Whh, bih, bhh, cpart_all);
    gates_gemm3<<<dim3(8, 16, 3), 256, 0, stream>>>(r0_all, Wih, cpart_all, gates_all);
    attn3_linear<<<P_PATH, 256, 0, stream>>>(x_cache, gates_all, bih, bhh, Wg, bg, xg);
    final_mlp<<<1, 256, 0, stream>>>(xg, Wl1, bl1, Wl2, bl2, Wl3, bl3, (float*)d_out);
}